// Round 4
// baseline (29.036 us; speedup 1.0000x reference)
//
#include <hip/hip_runtime.h>
#include <math.h>
#include <stdint.h>

constexpr int Hn = 512, Wn = 512, Bn = 16;
constexpr int GX = 2, GY = 32;       // block = 256 cols x 16 core rows
constexpr int NBLK = GX * GY * Bn;   // 1024 blocks
#define NACC 11
constexpr float NTOT = 16.f * 512.f * 512.f;

// partials (transposed [i][blk]): 0 bce, 1 sum_d, 2 sum_t, 3 sum_dt,
//   4..6 cnt(3,5,7), 7..9 bce*mask(3,5,7), 10 detail

__device__ __forceinline__ uint32_t bits4(float4 v) {
    return (uint32_t)(v.x > 0.5f) | ((uint32_t)(v.y > 0.5f) << 1) |
           ((uint32_t)(v.z > 0.5f) << 2) | ((uint32_t)(v.w > 0.5f) << 3);
}

__device__ __forceinline__ float sigm(float x) {
    const float z = __expf(-fabsf(x));
    const float r = __builtin_amdgcn_rcpf(1.f + z);
    return (x >= 0.f) ? r : 1.f - r;
}

__device__ __forceinline__ void px(float xc, float tc, float& dc, float& bc) {
    const float z = __expf(-fabsf(xc));
    const float r = __builtin_amdgcn_rcpf(1.f + z);
    const float p = (xc >= 0.f) ? r : 1.f - r;
    dc = p - tc;
    bc = fmaxf((1.f - 2.f * tc) * xc, 0.f) + __logf(1.f + z);
}

__global__ __launch_bounds__(256) void crack_main(
    const float* __restrict__ logits, const float* __restrict__ target,
    float* __restrict__ partials)
{
    __shared__ uint32_t s_pm[22][64];   // po[0:12) | pu[12:24) | m[24:28)
    __shared__ float s_d[18][256];      // d = sigmoid(x) - t, rows y0-1..y0+16
    __shared__ float s_red[4][NACC];

    const int tid = threadIdx.x, lane = tid & 63, wid = tid >> 6;
    const int x0 = blockIdx.x * 256, y0 = blockIdx.y * 16;
    const size_t base = (size_t)blockIdx.z * (size_t)(Hn * Wn);
    const bool leftE = (x0 == 0), rightE = (x0 + 256 >= Wn);
    const int gx = x0 + 4 * lane;

    uint32_t validm = 0xFFFu;                  // valid-column mask for erosion
    if (leftE && lane == 0)   validm = 0xFF0u;
    if (rightE && lane == 63) validm = 0x0FFu;

    // ---- phase 1a: horizontal morphology for 22 rows (y0-3 .. y0+18) ----
#pragma unroll
    for (int k = 0; k < 6; ++k) {
        const int r = wid + 4 * k;             // wave-uniform row index
        if (r < 22) {
            const int gy = y0 - 3 + r;
            const bool rowv = ((unsigned)gy < (unsigned)Hn);
            uint32_t w = 0u, wc = 0u;
            if (rowv) {
                const float* trow = target + base + (size_t)gy * Wn;
                const uint32_t m = bits4(*(const float4*)(trow + gx));
                uint32_t lw = 0u, rw = 0u;
                if (gx >= 4)      lw = bits4(*(const float4*)(trow + gx - 4));
                if (gx + 8 <= Wn) rw = bits4(*(const float4*)(trow + gx + 4));
                w = lw | (m << 4) | (rw << 8);     // bit b = col gx-4+b
                wc = (~w) & validm;
            }
            const uint32_t w1 = w  | (w  << 1) | (w  >> 1);
            const uint32_t w2 = w1 | (w1 << 1) | (w1 >> 1);
            const uint32_t w3 = w2 | (w2 << 1) | (w2 >> 1);
            const uint32_t u1 = wc | (wc << 1) | (wc >> 1);
            const uint32_t u2 = u1 | (u1 << 1) | (u1 >> 1);
            const uint32_t u3 = u2 | (u2 << 1) | (u2 >> 1);
            const uint32_t po = ((w1 >> 4) & 0xFu) | (((w2 >> 4) & 0xFu) << 4) |
                                (((w3 >> 4) & 0xFu) << 8);
            const uint32_t pu = ((u1 >> 4) & 0xFu) | (((u2 >> 4) & 0xFu) << 4) |
                                (((u3 >> 4) & 0xFu) << 8);
            s_pm[r][lane] = po | (pu << 12) | (((w >> 4) & 0xFu) << 24);
        }
    }

    // ---- phase 1b: d-field (18 rows), bce + elementwise sums (core rows) ----
    float4 d4[5], bce4[5];
    float sbce = 0.f, sd = 0.f, sdt = 0.f, stt = 0.f;
#pragma unroll
    for (int k = 0; k < 5; ++k) {
        const int j = wid + 4 * k;             // d-row 0..17, wave-uniform
        d4[k] = make_float4(0.f, 0.f, 0.f, 0.f);
        bce4[k] = make_float4(0.f, 0.f, 0.f, 0.f);
        if (j < 18) {
            const int gy = y0 - 1 + j;
            const bool rowv = ((unsigned)gy < (unsigned)Hn);
            if (rowv) {
                const float4 x = *(const float4*)(logits + base + (size_t)gy * Wn + gx);
                const float4 t = *(const float4*)(target + base + (size_t)gy * Wn + gx);
                float4 d, bc;
                px(x.x, t.x, d.x, bc.x); px(x.y, t.y, d.y, bc.y);
                px(x.z, t.z, d.z, bc.z); px(x.w, t.w, d.w, bc.w);
                d4[k] = d;
                if (j >= 1 && j <= 16) {       // core rows always valid
                    bce4[k] = bc;
                    sbce += bc.x + bc.y + bc.z + bc.w;
                    sd   += d.x + d.y + d.z + d.w;
                    sdt  += d.x * t.x + d.y * t.y + d.z * t.z + d.w * t.w;
                    stt  += t.x + t.y + t.z + t.w;
                }
            }
            *(float4*)&s_d[j][4 * lane] = d4[k];
        }
    }

    // ---- edge d columns (x0-1 / x0+256) for the Laplacian, core rows ----
    float dl = 0.f, dr = 0.f;
    if (lane < 16 && !leftE) {
        const int gy = y0 + lane;
        const float xl = logits[base + (size_t)gy * Wn + (x0 - 1)];
        const float tl = target[base + (size_t)gy * Wn + (x0 - 1)];
        dl = sigm(xl) - ((tl > 0.5f) ? 1.f : 0.f);
    }
    if (lane >= 32 && lane < 48 && !rightE) {
        const int gy = y0 + (lane - 32);
        const float xr = logits[base + (size_t)gy * Wn + (x0 + 256)];
        const float tr = target[base + (size_t)gy * Wn + (x0 + 256)];
        dr = sigm(xr) - ((tr > 0.5f) ? 1.f : 0.f);
    }

    __syncthreads();

    // ---- phase 2: vertical combine (boundary) + Laplacian, core rows ----
    float sb1 = 0.f, sb2 = 0.f, sb3 = 0.f, sdet = 0.f;
    int c1 = 0, c2 = 0, c3 = 0;
#pragma unroll
    for (int k = 0; k < 5; ++k) {
        const int j = wid + 4 * k;             // wave-uniform
        if (j >= 1 && j <= 16) {
            const uint32_t q0 = s_pm[j - 1][lane], q1 = s_pm[j][lane],
                           q2 = s_pm[j + 1][lane], q3 = s_pm[j + 2][lane],
                           q4 = s_pm[j + 3][lane], q5 = s_pm[j + 4][lane],
                           q6 = s_pm[j + 5][lane];
            const uint32_t o3 = q2 | q3 | q4;
            const uint32_t o5 = o3 | q1 | q5;
            const uint32_t o7 = o5 | q0 | q6;
            const uint32_t vo = (o3 & 0xFu) | (o5 & 0xF0u) | (o7 & 0xF00u);
            const uint32_t vu = ((o3 >> 12) & 0xFu) | ((o5 >> 12) & 0xF0u) |
                                ((o7 >> 12) & 0xF00u);
            const uint32_t b = vo & vu;        // [0:4) r1, [4:8) r2, [8:12) r3
            c1 += __popc(b & 0xFu);
            c2 += __popc(b & 0xF0u);
            c3 += __popc(b & 0xF00u);
            const float4 bc = bce4[k];
            sb1 += (((b >> 0) & 1) ? bc.x : 0.f) + (((b >> 1) & 1) ? bc.y : 0.f) +
                   (((b >> 2) & 1) ? bc.z : 0.f) + (((b >> 3) & 1) ? bc.w : 0.f);
            sb2 += (((b >> 4) & 1) ? bc.x : 0.f) + (((b >> 5) & 1) ? bc.y : 0.f) +
                   (((b >> 6) & 1) ? bc.z : 0.f) + (((b >> 7) & 1) ? bc.w : 0.f);
            sb3 += (((b >> 8) & 1) ? bc.x : 0.f) + (((b >> 9) & 1) ? bc.y : 0.f) +
                   (((b >> 10) & 1) ? bc.z : 0.f) + (((b >> 11) & 1) ? bc.w : 0.f);

            const float4 dc = d4[k];
            const float4 du = *(const float4*)&s_d[j - 1][4 * lane];
            const float4 dd = *(const float4*)&s_d[j + 1][4 * lane];
            float left = __shfl_up(dc.w, 1);
            { const float el = __shfl(dl, j - 1); if (lane == 0)  left = el; }
            float right = __shfl_down(dc.x, 1);
            { const float er = __shfl(dr, 32 + j - 1); if (lane == 63) right = er; }
            sdet += fabsf(left + dc.y + du.x + dd.x - 4.f * dc.x);
            sdet += fabsf(dc.x + dc.z + du.y + dd.y - 4.f * dc.y);
            sdet += fabsf(dc.y + dc.w + du.z + dd.z - 4.f * dc.z);
            sdet += fabsf(dc.z + right + du.w + dd.w - 4.f * dc.w);
        }
    }

    // ---- block reduction ----
    float acc[NACC];
    acc[0] = sbce; acc[1] = sd; acc[2] = stt; acc[3] = sdt;
    acc[4] = (float)c1; acc[5] = (float)c2; acc[6] = (float)c3;
    acc[7] = sb1; acc[8] = sb2; acc[9] = sb3; acc[10] = sdet;
#pragma unroll
    for (int i = 0; i < NACC; ++i) {
        float v = acc[i];
#pragma unroll
        for (int off = 32; off; off >>= 1) v += __shfl_xor(v, off);
        acc[i] = v;
    }
    if (lane == 0) {
#pragma unroll
        for (int i = 0; i < NACC; ++i) s_red[wid][i] = acc[i];
    }
    __syncthreads();
    if (tid < NACC) {
        const int bid = (blockIdx.z * GY + blockIdx.y) * GX + blockIdx.x;
        partials[(size_t)tid * NBLK + bid] =
            s_red[0][tid] + s_red[1][tid] + s_red[2][tid] + s_red[3][tid];
    }
}

__global__ __launch_bounds__(256) void crack_final(
    const float* __restrict__ partials, float* __restrict__ out)
{
    const int tid = threadIdx.x;
    float a[NACC];
#pragma unroll
    for (int i = 0; i < NACC; ++i) a[i] = 0.f;
    for (int b = tid; b < NBLK; b += 256) {
#pragma unroll
        for (int i = 0; i < NACC; ++i) a[i] += partials[(size_t)i * NBLK + b];
    }
#pragma unroll
    for (int i = 0; i < NACC; ++i) {
        float v = a[i];
#pragma unroll
        for (int off = 32; off; off >>= 1) v += __shfl_xor(v, off);
        a[i] = v;
    }
    __shared__ float s_red[4][NACC];
    const int lane = tid & 63, wid = tid >> 6;
    if (lane == 0) {
#pragma unroll
        for (int i = 0; i < NACC; ++i) s_red[wid][i] = a[i];
    }
    __syncthreads();
    if (tid == 0) {
        float t[NACC];
        for (int i = 0; i < NACC; ++i)
            t[i] = s_red[0][i] + s_red[1][i] + s_red[2][i] + s_red[3][i];
        const float bce   = t[0] / NTOT;
        const float st    = t[2];
        const float sp    = t[1] + t[2];
        const float inter = t[3] + t[2];
        const float dice = 1.f - (2.f * inter + 1.f) / (sp + st + 1.f);
        const float fp = sp - inter, fn = st - inter;
        const float tvi = (inter + 1.f) / (inter + 0.6f * fp + 0.4f * fn + 1.f);
        const float tversky = powf(fmaxf(1.f - tvi, 0.f), 0.75f);
        float tb = 0.f, ns = 0.f;
        for (int i = 0; i < 3; ++i) {
            const float cnt = t[4 + i], sb = t[7 + i];
            if (cnt >= 1.f) { tb += sb / cnt; ns += 1.f; }
        }
        const float boundary = (ns > 0.f) ? tb / ns : 0.f;
        const float detail = t[10] / NTOT;
        out[0] = bce + dice + 0.5f * tversky + 0.5f * boundary + 0.3f * detail;
    }
}

extern "C" void kernel_launch(void* const* d_in, const int* in_sizes, int n_in,
                              void* d_out, int out_size, void* d_ws, size_t ws_size,
                              hipStream_t stream) {
    const float* logits = (const float*)d_in[0];
    const float* target = (const float*)d_in[1];
    float* partials = (float*)d_ws;   // NACC * NBLK floats = 45 KiB

    dim3 grid(GX, GY, Bn);
    crack_main<<<grid, dim3(256), 0, stream>>>(logits, target, partials);
    crack_final<<<1, 256, 0, stream>>>(partials, (float*)d_out);
}